// Round 1
// 1034.525 us; speedup vs baseline: 1.4868x; 1.4868x over previous
//
#include <hip/hip_runtime.h>
#include <cstdint>
#include <cstddef>

#define BATCH   32768
#define DIM     768
#define POOL    20
#define TOPK    9

// ws layout:
//   [0,      61440)  kn      float[20*768]   (normalized keys[layer])
//   [61440,  61520)  cnt     int[20]         (global top-k index histogram)
//   [61568,  61728)  rowsum  double[20]      (sum over pools of sim row r, r<20)

__global__ __launch_bounds__(256) void prep_kernel(
    const float* __restrict__ keys, const int* __restrict__ layerp,
    float* __restrict__ kn, int* __restrict__ cnt)
{
    const int layer = *layerp;
    const int tid  = threadIdx.x;
    const int lane = tid & 63;
    const int wid  = tid >> 6;
    if (tid < POOL) cnt[tid] = 0;
    for (int r = wid; r < POOL; r += 4) {
        const float* krow = keys + ((size_t)layer * POOL + r) * DIM;
        float v[12];
        double ss = 0.0;
#pragma unroll
        for (int j = 0; j < 12; ++j) {
            v[j] = krow[lane + 64 * j];
            ss += (double)v[j] * (double)v[j];
        }
#pragma unroll
        for (int off = 32; off >= 1; off >>= 1) ss += __shfl_xor(ss, off);
        float n = fmaxf((float)sqrt(ss), 1e-12f);
#pragma unroll
        for (int j = 0; j < 12; ++j)
            kn[(size_t)r * DIM + lane + 64 * j] = v[j] / n;
    }
}

// 512 threads (8 waves). Each wave: 4 rows concurrently (16 lanes/row), 2 quads.
// 512 blocks * 8 waves * 2 quads * 4 rows = 32768 rows.
// Occupancy: LDS 61440 -> 2 blocks/CU -> 16 waves/CU; launch_bounds(512,4) caps VGPR at 128.
__global__ __launch_bounds__(512, 4) void pool_main(
    const float* __restrict__ x, const float* __restrict__ prompts,
    const int* __restrict__ layerp, const float* __restrict__ kn,
    float* __restrict__ out, int* __restrict__ cnt, double* __restrict__ rowsum)
{
    __shared__ float4 knl4[POOL * DIM / 4];   // 61440 B

    const int tid  = threadIdx.x;
    const int lane = tid & 63;
    const int wid  = tid >> 6;      // 0..7
    const int s    = lane & 15;     // lane within 16-lane group
    const int g    = lane >> 4;     // group (row slot) 0..3

    // stage normalized keys to LDS (15360 float4 / 512 threads = 30 each)
    {
        const float4* src = (const float4*)kn;
#pragma unroll
        for (int i = 0; i < 30; ++i) knl4[tid + 512 * i] = src[tid + 512 * i];
    }
    __syncthreads();

    const float* knl   = (const float*)knl4;
    const int    layer = *layerp;
    const float* pl    = prompts + (size_t)layer * POOL * DIM;  // LEN_PROMPTS == 1

    const int w = blockIdx.x * 8 + wid;    // global wave id 0..4095
    int c0 = 0, c1 = 0;                    // per-lane histogram regs (pools s, s+16)

#pragma unroll 1
    for (int qi = 0; qi < 2; ++qi) {
        const int quad = w * 2 + qi;           // 0..8191
        const int row  = quad * 4 + g;         // this group's row
        const float* xr = x + (size_t)row * DIM + s * 4;

        // ---- pass 1: L2 norm of x row (f64 accumulate, 4-step group butterfly) ----
        double ss = 0.0;
#pragma unroll
        for (int c = 0; c < 12; ++c) {
            float4 v = *(const float4*)(xr + c * 64);
            ss += (double)v.x * (double)v.x;
            ss += (double)v.y * (double)v.y;
            ss += (double)v.z * (double)v.z;
            ss += (double)v.w * (double)v.w;
        }
        ss += __shfl_xor(ss, 8);
        ss += __shfl_xor(ss, 4);
        ss += __shfl_xor(ss, 2);
        ss += __shfl_xor(ss, 1);
        const float n = fmaxf((float)sqrt(ss), 1e-12f);

        // ---- pass 2: 20 dot products, f64 accumulate into registers ----
        double acc[POOL];
#pragma unroll
        for (int p = 0; p < POOL; ++p) acc[p] = 0.0;

#pragma unroll 1
        for (int c = 0; c < 12; ++c) {
            float4 v = *(const float4*)(xr + c * 64);   // L1-hot re-read
            v.x /= n; v.y /= n; v.z /= n; v.w /= n;     // fp32 xn, matches ref rounding
            const double x0 = (double)v.x, x1 = (double)v.y,
                         x2 = (double)v.z, x3 = (double)v.w;
            const float* kb = knl + c * 64 + s * 4;
#pragma unroll
            for (int p = 0; p < POOL; ++p) {
                float4 k = *(const float4*)(kb + p * DIM);
                acc[p] = fma(x0, (double)k.x, acc[p]);
                acc[p] = fma(x1, (double)k.y, acc[p]);
                acc[p] = fma(x2, (double)k.z, acc[p]);
                acc[p] = fma(x3, (double)k.w, acc[p]);
            }
        }

        // ---- batched butterfly: 20 doubles x 4 steps (stays within 16-lane group) ----
#pragma unroll
        for (int off = 8; off >= 1; off >>= 1) {
#pragma unroll
            for (int p = 0; p < POOL; ++p) acc[p] += __shfl_xor(acc[p], off);
        }
        // all 16 lanes of the group now hold all 20 sims (uniform within group)

        // ---- rowsum for dist (rows < POOL only) ----
        if (row < POOL && s == 0) {
            double rs = 0.0;
#pragma unroll
            for (int p = 0; p < POOL; ++p) rs += acc[p];
            rowsum[row] = rs;
        }

        // ---- top-9 (pure VALU, uniform within group) fused with gather-write ----
        float* orow = out + (size_t)row * (TOPK * DIM) + s * 4;
#pragma unroll 1
        for (int t = 0; t < TOPK; ++t) {
            double bv = acc[0]; int bi = 0;
#pragma unroll
            for (int p = 1; p < POOL; ++p) {
                if (acc[p] > bv) { bv = acc[p]; bi = p; }   // strict > : tie -> lower index
            }
#pragma unroll
            for (int p = 0; p < POOL; ++p) {
                if (p == bi) acc[p] = -1e300;               // remove winner (cndmask)
            }
            c0 += (bi == s)      ? 1 : 0;
            c1 += (bi == s + 16) ? 1 : 0;                   // only s<4 can ever match

            const float* src = pl + (size_t)bi * DIM + s * 4;
            float* dst = orow + t * DIM;
#pragma unroll
            for (int c = 0; c < 12; ++c) {
                *(float4*)(dst + c * 64) = *(const float4*)(src + c * 64);
            }
        }
    }

    // ---- histogram: reduce the 4 groups, then <=2 global atomics per wave ----
    c0 += __shfl_xor(c0, 16);
    c0 += __shfl_xor(c0, 32);
    c1 += __shfl_xor(c1, 16);
    c1 += __shfl_xor(c1, 32);
    if (lane < 16 && c0) atomicAdd(&cnt[lane], c0);
    if (lane < 4  && c1) atomicAdd(&cnt[16 + lane], c1);
}

__global__ __launch_bounds__(64) void finalize_kernel(
    const int* __restrict__ cnt, const double* __restrict__ rowsum,
    float* __restrict__ out)
{
    const int lane = threadIdx.x & 63;
    double v = (lane < POOL) ? (double)cnt[lane] * rowsum[lane] : 0.0;
#pragma unroll
    for (int off = 32; off >= 1; off >>= 1) v += __shfl_xor(v, off);
    if (lane == 0) {
        const double denom = (double)BATCH * TOPK * POOL;
        out[(size_t)BATCH * TOPK * DIM] = (float)(1.0 - v / denom);
    }
}

extern "C" void kernel_launch(void* const* d_in, const int* in_sizes, int n_in,
                              void* d_out, int out_size, void* d_ws, size_t ws_size,
                              hipStream_t stream) {
    const float* x       = (const float*)d_in[0];
    const float* keys    = (const float*)d_in[1];
    const float* prompts = (const float*)d_in[2];
    const int*   layerp  = (const int*)d_in[3];
    float* out = (float*)d_out;

    char*   ws     = (char*)d_ws;
    float*  kn     = (float*)ws;
    int*    cnt    = (int*)(ws + 61440);
    double* rowsum = (double*)(ws + 61568);

    prep_kernel<<<1, 256, 0, stream>>>(keys, layerp, kn, cnt);
    pool_main<<<512, 512, 0, stream>>>(x, prompts, layerp, kn, out, cnt, rowsum);
    finalize_kernel<<<1, 64, 0, stream>>>(cnt, rowsum, out);
}